// Round 7
// baseline (152.122 us; speedup 1.0000x reference)
//
#include <hip/hip_runtime.h>
#include <math.h>

#define SM_WSUM 0
#define SM_RWS  1
#define SM_Q00  2
#define SM_Z2   4
#define SM_BS   16
#define SM_W    48
#define SM_G    148
#define SM_GV   248
#define SM_BW   260
#define SM_SIZE 292

// arena (floats). Phase P and Phase A usages barrier-separated.
// Phase P: s_mk/barb 0..2999, w 3000, sw 3104, bw 3208, C 3240, Hi 3340,
//          G 3440, T 3540, gv 3640, Ht 3656, z 3672  (as R5)
// Phase A: sF [16][90] @0, sQl [16][57] @1440, sG3 [16][9] @2352, sYW [16][4] @2496
#define AR_SIZE 3712

__host__ __device__ constexpr int TRI(int p,int q){ return p*10-(p*(p+1))/2+q; } // p<=q
__host__ __device__ constexpr int SIDX(int a,int b){ return (a<=b)?TRI(a,b):TRI(b,a); }
__host__ __device__ constexpr int LTRI(int i,int j){ return i*(i+1)/2+j; }       // j<=i

template<int CTRL>
__device__ __forceinline__ float dpp_add(float v){
  int s = __builtin_amdgcn_mov_dpp(__float_as_int(v), CTRL, 0xF, 0xF, true);
  return v + __int_as_float(s);
}
// 16-lane group sum (DPP row = 16 lanes)
__device__ __forceinline__ float gsum16(float v){
  v = dpp_add<0xB1>(v);    // quad xor1
  v = dpp_add<0x4E>(v);    // quad xor2
  v = dpp_add<0x141>(v);   // row_half_mirror
  v = dpp_add<0x140>(v);   // row_mirror
  return v;
}

__global__ __launch_bounds__(256,2) void pace_fused(const float* __restrict__ y,
                                                    const float* __restrict__ w,
                                                    const float* __restrict__ mk,
                                                    float* __restrict__ out){
  __shared__ __attribute__((aligned(16))) float sc[3600];     // coef rows [n][36]
  __shared__ float sm[SM_SIZE];
  __shared__ __attribute__((aligned(16))) float arena[AR_SIZE];
  const int tid  = threadIdx.x;
  const int lane = tid & 63;
  const int sub  = tid & 15;
  const int item = tid >> 4;                 // 0..15
  const int gb   = blockIdx.x*16 + item;
  const float* yb = y + gb*300;

  // ================= Phase P: per-block precompute (identical across blocks) =================
  {
    float* s_mb = arena;          // 3000: mk staged, then bar_b in place
    float* s_w  = arena+3000;
    float* s_sw = arena+3104;
    float* s_bw = arena+3208;
    float* s_C  = arena+3240;
    float* s_Hi = arena+3340;
    float* s_G  = arena+3440;
    float* s_T  = arena+3540;
    float* s_gv = arena+3640;
    float* s_Ht = arena+3656;
    float* s_z  = arena+3672;

    for (int i=tid;i<3000;i+=256) s_mb[i]=mk[i];
    for (int i=tid;i<100;i+=256){ float x=w[i]; s_w[i]=x; s_sw[i]=sqrtf(x); }
    __syncthreads();

    // wsum: per-wave butterfly (identical in all waves)
    float av = s_w[lane] + ((lane<36)? s_w[lane+64] : 0.f);
    #pragma unroll
    for (int m=32;m;m>>=1) av += __shfl_xor(av,m);
    const float wsum = av;
    const float rws  = 1.0f/av;

    if (tid<30){      // b_w rows
      const float4* p=(const float4*)&s_mb[tid*100];
      const float4* q=(const float4*)&s_w[0];
      float acc=0;
      #pragma unroll 5
      for (int j=0;j<25;j++){ float4 x=p[j], yv=q[j];
        acc=fmaf(x.x,yv.x,acc); acc=fmaf(x.y,yv.y,acc);
        acc=fmaf(x.z,yv.z,acc); acc=fmaf(x.w,yv.w,acc); }
      s_bw[tid]=acc*rws;
    }
    __syncthreads();
    for (int i=tid;i<3000;i+=256){ int r=i/100, n=i-r*100; s_mb[i]=s_sw[n]*(s_mb[i]-s_bw[r]); }
    __syncthreads();
    // C = bar_B^T bar_B from LDS (one element per thread, tid<100)
    if (tid<100){
      int k=tid/10, k2=tid-10*(tid/10);
      const float4* p1=(const float4*)&s_mb[k*300];
      const float4* p2=(const float4*)&s_mb[k2*300];
      float acc=0;
      #pragma unroll 5
      for (int j=0;j<75;j++){ float4 x=p1[j], yv=p2[j];
        acc=fmaf(x.x,yv.x,acc); acc=fmaf(x.y,yv.y,acc);
        acc=fmaf(x.z,yv.z,acc); acc=fmaf(x.w,yv.w,acc); }
      s_C[tid]=acc;
    }
    __syncthreads();
    // Gauss-Jordan inversion of 2(C+I): wave0 lanes 0..9 own rows
    if (tid<64){
      float R[20];
      {
        int row=(tid<10)? tid : 0;
        #pragma unroll
        for (int c=0;c<10;c++) R[c]=2.0f*(s_C[row*10+c]+(c==row?1.0f:0.0f));
        #pragma unroll
        for (int c=0;c<10;c++) R[10+c]=(c==row)?1.0f:0.0f;
      }
      #pragma unroll
      for (int p=0;p<10;p++){
        float appv=__shfl(R[p],p);
        float ra=1.0f/appv;
        float fr=R[p];
        #pragma unroll
        for (int c=0;c<20;c++){
          float pc=__shfl(R[c],p)*ra;
          R[c]=(tid==p)? pc : fmaf(-fr,pc,R[c]);
        }
      }
      if (tid<10){
        float ht=0.f;
        #pragma unroll
        for (int c=0;c<10;c++){ s_Hi[tid*10+c]=R[10+c]; ht+=R[10+c]; }
        s_Ht[tid]=ht;
      }
    }
    __syncthreads();
    // denom from LDS (uniform across all threads)
    float dsum=0.f;
    #pragma unroll
    for (int k=0;k<10;k++) dsum+=s_Ht[k];
    const float rden=1.0f/dsum;
    if (tid<10) s_gv[tid]=s_Ht[tid]*rden;
    __syncthreads();
    if (tid<100){ int r=tid/10,c=tid-10*(tid/10); s_G[tid]=s_Hi[tid]-s_Ht[r]*s_Ht[c]*rden; }
    __syncthreads();
    if (tid<100){         // T = (C+I)G
      int r=tid/10,c=tid-10*(tid/10); float acc=0;
      #pragma unroll
      for (int j=0;j<10;j++) acc+=(s_C[r*10+j]+(r==j?1.0f:0.0f))*s_G[j*10+c];
      s_T[tid]=acc;
    }
    __syncthreads();
    if (tid<100){         // W = 4G(C+I)G - 4G ; emit G
      int r=tid/10,c=tid-10*(tid/10); float acc=0;
      #pragma unroll
      for (int j=0;j<10;j++) acc+=s_G[r*10+j]*s_T[j*10+c];
      sm[SM_W+tid]=4.0f*acc-4.0f*s_G[tid];
      sm[SM_G+tid]=s_G[tid];
    }
    if (tid<10){          // z = (C+I)g
      float acc=0;
      #pragma unroll
      for (int j=0;j<10;j++) acc+=(s_C[tid*10+j]+(tid==j?1.0f:0.0f))*s_gv[j];
      s_z[tid]=acc;
    }
    __syncthreads();
    if (tid<10){          // z2 = 2Gz - g
      float acc=0;
      #pragma unroll
      for (int j=0;j<10;j++) acc+=s_G[tid*10+j]*s_z[j];
      sm[SM_Z2+tid]=2.0f*acc-s_gv[tid];
    }
    if (tid==0){          // q00 = g^T C g + g.g (serial, tiny)
      float acc=0;
      #pragma unroll
      for (int r=0;r<10;r++){
        float rr=0;
        #pragma unroll
        for (int c=0;c<10;c++) rr+=s_C[r*10+c]*s_gv[c];
        acc+=s_gv[r]*rr+s_gv[r]*s_gv[r];
      }
      sm[SM_WSUM]=wsum; sm[SM_RWS]=rws; sm[SM_Q00]=acc; sm[3]=0.f;
    }
    // coef rows [n][36]: {w, coef0..29, pad5}; coef = sw*barb = w*(b-bw)
    for (int i=tid;i<3600;i+=256){
      int n=i/36, e=i-36*n; float v;
      if (e==0) v=s_w[n];
      else if (e>=31) v=0.f;
      else v=s_mb[(e-1)*100+n]*s_sw[n];
      sc[i]=v;
    }
    if (tid<30){          // bs[k,j] = sum_n barb*sw
      const float4* p=(const float4*)&s_mb[tid*100];
      const float4* q=(const float4*)&s_sw[0];
      float acc=0;
      #pragma unroll 5
      for (int j=0;j<25;j++){ float4 x=p[j], yv=q[j];
        acc=fmaf(x.x,yv.x,acc); acc=fmaf(x.y,yv.y,acc);
        acc=fmaf(x.z,yv.z,acc); acc=fmaf(x.w,yv.w,acc); }
      sm[SM_BS+tid]=acc;
    }
    if (tid<10) sm[SM_GV+tid]=s_gv[tid];
    if (tid<30) sm[SM_BW+tid]=s_bw[tid];
    __syncthreads();   // Phase P done; arena reusable
  }

  // ================= Phase A: 16 lanes per item =================
  float* sF  = arena;          // [16][90]
  float* sQl = arena+1440;     // [16][57]  (stride 57: conflict-free lane reads)
  float* sG3 = arena+2352;     // [16][9]
  float* sYW = arena+2496;     // [16][4]

  {
    float F0[90];
    #pragma unroll
    for (int i=0;i<90;i++) F0[i]=0.f;
    float swy0=0,swy1=0,swy2=0,s00=0,s01=0,s02=0,s11=0,s12=0,s22=0;

    auto point=[&](int n){
      float y0=yb[n], y1=yb[100+n], y2=yb[200+n];
      float c[32];
      const float4* cp=(const float4*)&sc[n*36];
      #pragma unroll
      for (int r=0;r<8;r++) ((float4*)c)[r]=cp[r];
      float wn=c[0];
      float wy0=wn*y0,wy1=wn*y1,wy2=wn*y2;
      swy0+=wy0;swy1+=wy1;swy2+=wy2;
      s00+=wy0*y0;s01+=wy0*y1;s02+=wy0*y2;s11+=wy1*y1;s12+=wy1*y2;s22+=wy2*y2;
      #pragma unroll
      for (int k=0;k<10;k++){
        #pragma unroll
        for (int j=0;j<3;j++){
          float bcv=c[1+k*3+j];
          F0[k*9+j*3+0]+=bcv*y0;
          F0[k*9+j*3+1]+=bcv*y1;
          F0[k*9+j*3+2]+=bcv*y2;
        }
      }
    };
    #pragma unroll
    for (int m=0;m<6;m++) point(sub+16*m);
    if (sub<4) point(96+sub);

    #pragma unroll
    for (int e=0;e<90;e++) F0[e]=gsum16(F0[e]);
    swy0=gsum16(swy0); swy1=gsum16(swy1); swy2=gsum16(swy2);
    s00=gsum16(s00); s01=gsum16(s01); s02=gsum16(s02);
    s11=gsum16(s11); s12=gsum16(s12); s22=gsum16(s22);

    const float wsum=sm[SM_WSUM], rws=sm[SM_RWS];
    const float yw0=swy0*rws, yw1=swy1*rws, yw2=swy2*rws;
    #pragma unroll
    for (int k=0;k<10;k++){
      float bs0=sm[SM_BS+k*3+0],bs1=sm[SM_BS+k*3+1],bs2=sm[SM_BS+k*3+2];
      F0[k*9+0]-=yw0*bs0; F0[k*9+1]-=yw1*bs0; F0[k*9+2]-=yw2*bs0;
      F0[k*9+3]-=yw0*bs1; F0[k*9+4]-=yw1*bs1; F0[k*9+5]-=yw2*bs1;
      F0[k*9+6]-=yw0*bs2; F0[k*9+7]-=yw1*bs2; F0[k*9+8]-=yw2*bs2;
    }
    // spread the F store across the 16 subs
    for (int e=sub;e<90;e+=16) sF[item*90+e]=F0[e];
    if (sub==0){
      sG3[item*9+0]=s00-wsum*yw0*yw0;
      sG3[item*9+4]=s11-wsum*yw1*yw1;
      sG3[item*9+8]=s22-wsum*yw2*yw2;
      float g01=s01-wsum*yw0*yw1, g02=s02-wsum*yw0*yw2, g12=s12-wsum*yw1*yw2;
      sG3[item*9+1]=g01; sG3[item*9+3]=g01;
      sG3[item*9+2]=g02; sG3[item*9+6]=g02;
      sG3[item*9+5]=g12; sG3[item*9+7]=g12;
      sYW[item*4+0]=yw0; sYW[item*4+1]=yw1; sYW[item*4+2]=yw2;
    }
  }
  __syncthreads();

  // ---- Q assembly: 144 column tasks (item,mp) + 16 q00 writes ----
  if (tid<144){
    int it2=tid/9, mp=tid-9*(tid/9);
    float fcol[10], t2[10];
    #pragma unroll
    for (int k=0;k<10;k++) fcol[k]=sF[it2*90+k*9+mp];
    #pragma unroll
    for (int k=0;k<10;k++){
      float acc=0;
      #pragma unroll
      for (int k2=0;k2<10;k2++) acc+=sm[SM_W+k*10+k2]*fcol[k2];
      t2[k]=acc;
    }
    float he=0;
    #pragma unroll
    for (int k=0;k<10;k++) he+=sm[SM_Z2+k]*fcol[k];
    sQl[it2*57 + 1+mp]=he;
    #pragma unroll 1
    for (int m=0;m<=mp;m++){
      float gd=sG3[it2*9+(m%3)*3+(mp%3)];
      float acc=((m/3)==(mp/3))? gd : 0.f;
      #pragma unroll
      for (int k=0;k<10;k++) acc+=sF[it2*90+k*9+m]*t2[k];
      int p=1+m, q=1+mp;
      sQl[it2*57 + p*10-((p*(p+1))>>1)+q]=acc;
    }
  }
  if (tid>=144 && tid<160) sQl[(tid-144)*57]=sm[SM_Q00];
  __syncthreads();

  // ================= Eigen + epilogue: one item per thread (tid<16) =================
  if (tid<16){
    const int it2=tid;
    const int gb2=blockIdx.x*16+it2;
    float A[55];
    #pragma unroll
    for (int e=0;e<55;e++) A[e]=sQl[it2*57+e];
    float dd[10], ee[9];
    #pragma unroll
    for (int k=0;k<8;k++){
      float nrm2=0.f;
      #pragma unroll
      for (int i=1;i<10;i++){ if (i<k+1) continue; float xi=A[SIDX(i,k)]; nrm2=fmaf(xi,xi,nrm2); }
      float x0=A[SIDX(k+1,k)];
      float nr=sqrtf(nrm2);
      float alpha=-copysignf(nr,x0);
      bool ok=nrm2>1e-30f;
      float v1=x0-alpha;
      float vtv=-2.0f*alpha*v1;
      float bh=ok?2.0f*__builtin_amdgcn_rcpf(vtv):0.f;
      ee[k]=ok?alpha:x0;
      float vv[10];
      #pragma unroll
      for (int i=0;i<10;i++) vv[i]=(i<k+1)?0.f:((i==k+1)?v1:A[SIDX(i,k)]);
      float p[10];
      #pragma unroll
      for (int i=0;i<10;i++){
        if (i<k+1){ p[i]=0.f; continue; }
        float acc=0;
        #pragma unroll
        for (int j=1;j<10;j++){ if (j<k+1) continue; acc+=A[SIDX(i,j)]*vv[j]; }
        p[i]=bh*acc;
      }
      float Kc=0.f;
      #pragma unroll
      for (int i=1;i<10;i++){ if (i<k+1) continue; Kc=fmaf(vv[i],p[i],Kc); }
      Kc*=0.5f*bh;
      float wv[10];
      #pragma unroll
      for (int i=0;i<10;i++) wv[i]=p[i]-Kc*vv[i];
      #pragma unroll
      for (int i=1;i<10;i++){
        if (i<k+1) continue;
        #pragma unroll
        for (int j=1;j<10;j++){
          if (j<i) continue;
          A[TRI(i,j)]-=vv[i]*wv[j]+wv[i]*vv[j];
        }
      }
    }
    ee[8]=A[TRI(8,9)];
    #pragma unroll
    for (int i=0;i<10;i++) dd[i]=A[TRI(i,i)];
    float esq[9];
    #pragma unroll
    for (int i=0;i<9;i++) esq[i]=ee[i]*ee[i];

    // Gershgorin bracket + serial bisection (16 iters)
    float scaleT=0.f, lo=1e30f, hi=1e30f;
    #pragma unroll
    for (int i=0;i<10;i++){
      float r=((i>0)?fabsf(ee[i-1]):0.f)+((i<9)?fabsf(ee[i]):0.f);
      scaleT=fmaxf(scaleT,fabsf(dd[i])+r);
      lo=fminf(lo,dd[i]-r);
      hi=fminf(hi,dd[i]);
    }
    hi+=1e-6f*scaleT+1e-30f;
    const float pm=1e-12f*scaleT+1e-37f;
    #pragma unroll 1
    for (int it=0;it<16;++it){
      float mid=0.5f*(lo+hi);
      float q=dd[0]-mid;
      q=(fabsf(q)<pm)?((q<0.f)?-pm:pm):q;
      int cnt=(q<0.f);
      #pragma unroll
      for (int i=1;i<10;i++){
        q=dd[i]-mid-esq[i-1]*__builtin_amdgcn_rcpf(q);
        q=(fabsf(q)<pm)?((q<0.f)?-pm:pm):q;
        cnt+=(q<0.f);
      }
      bool any=cnt>0;
      hi=any?mid:hi;
      lo=any?lo:mid;
    }
    const float sigma=lo-1e-5f*scaleT-1e-30f;   // cnt(sigma)==0; margin caps amplification
    const float pmL=1e-8f*scaleT+1e-37f;

    // dense Cholesky of (Q - sigma I) from LDS; overflow rails
    float Lc[55], rd[10];
    #pragma unroll
    for (int i=0;i<10;i++){
      #pragma unroll
      for (int j=0;j<10;j++){
        if (j>i) continue;
        float a=sQl[it2*57+SIDX(j,i)]-((i==j)?sigma:0.f);
        #pragma unroll
        for (int t2=0;t2<9;t2++){
          if (t2>=j) continue;
          a-=Lc[LTRI(i,t2)]*Lc[LTRI(j,t2)];
        }
        if (j<i) Lc[LTRI(i,j)]=a*rd[j];
        else { a=fmaxf(a,pmL); rd[i]=rsqrtf(a); Lc[LTRI(i,i)]=a*rd[i]; }
      }
    }
    float xv[10];
    #pragma unroll
    for (int i=0;i<10;i++) xv[i]=1.f;
    #pragma unroll 1
    for (int itr=0;itr<3;++itr){
      #pragma unroll
      for (int i=0;i<10;i++){
        float acc=xv[i];
        #pragma unroll
        for (int j=0;j<9;j++){ if (j>=i) continue; acc-=Lc[LTRI(i,j)]*xv[j]; }
        acc*=rd[i];
        xv[i]=fminf(fmaxf(acc,-1e15f),1e15f);
      }
      #pragma unroll
      for (int i=9;i>=0;i--){
        float acc=xv[i];
        #pragma unroll
        for (int j=9;j>0;j--){ if (j<=i) continue; acc-=Lc[LTRI(j,i)]*xv[j]; }
        acc*=rd[i];
        xv[i]=fminf(fmaxf(acc,-1e15f),1e15f);
      }
      float nn=0.f;
      #pragma unroll
      for (int i=0;i<10;i++) nn=fmaf(xv[i],xv[i],nn);
      nn=fmaxf(nn,1e-30f);
      float sc2=rsqrtf(nn);
      #pragma unroll
      for (int i=0;i<10;i++) xv[i]*=sc2;
    }
    float r0=1.0f/xv[0];
    float vn[10];
    vn[0]=1.f;
    #pragma unroll
    for (int m=1;m<10;m++) vn[m]=xv[m]*r0;

    // epilogue
    float dv[10];
    #pragma unroll
    for (int k=0;k<10;k++){
      float acc=0;
      #pragma unroll
      for (int m=0;m<9;m++) acc+=vn[1+m]*sF[it2*90+k*9+m];
      dv[k]=acc;
    }
    float cv[10];
    #pragma unroll
    for (int k=0;k<10;k++){
      float acc=0;
      #pragma unroll
      for (int k2=0;k2<10;k2++) acc+=sm[SM_G+k*10+k2]*dv[k2];
      cv[k]=2.0f*acc+sm[SM_GV+k];
    }
    float e0=0,e1=0,e2=0;
    #pragma unroll
    for (int k=0;k<10;k++){
      e0+=sm[SM_BW+k*3+0]*cv[k];
      e1+=sm[SM_BW+k*3+1]*cv[k];
      e2+=sm[SM_BW+k*3+2]*cv[k];
    }
    float yw0=sYW[it2*4+0], yw1=sYW[it2*4+1], yw2=sYW[it2*4+2];
    #pragma unroll
    for (int i=0;i<3;i++)
      #pragma unroll
      for (int j=0;j<3;j++)
        out[gb2*9+i*3+j]=vn[1+3*j+i];
    out[73728+gb2*3+0]=yw0-(vn[1]*e0+vn[4]*e1+vn[7]*e2);
    out[73728+gb2*3+1]=yw1-(vn[2]*e0+vn[5]*e1+vn[8]*e2);
    out[73728+gb2*3+2]=yw2-(vn[3]*e0+vn[6]*e1+vn[9]*e2);
    #pragma unroll
    for (int k=0;k<10;k++)
      out[98304+gb2*10+k]=cv[k];
  }
}

extern "C" void kernel_launch(void* const* d_in, const int* in_sizes, int n_in,
                              void* d_out, int out_size, void* d_ws, size_t ws_size,
                              hipStream_t stream) {
  const float* y  = (const float*)d_in[0];   // (8192,3,100)
  const float* w  = (const float*)d_in[1];   // (100,1)
  const float* mk = (const float*)d_in[2];   // (10,3,100)
  float* out = (float*)d_out;                // R(8192*9) | t(8192*3) | c(8192*10)
  pace_fused<<<512, 256, 0, stream>>>(y, w, mk, out);
}

// Round 8
// 103.167 us; speedup vs baseline: 1.4745x; 1.4745x over previous
//
#include <hip/hip_runtime.h>
#include <math.h>

#define SM_WSUM 0
#define SM_RWS  1
#define SM_Q00  2
#define SM_Z2   4
#define SM_BS   16
#define SM_W    48
#define SM_G    148
#define SM_GV   248
#define SM_BW   260
#define SM_SIZE 292

// arena (floats). Phase P and Phase A usages barrier-separated.
#define AR_SIZE 3712

__host__ __device__ constexpr int TRI(int p,int q){ return p*10-(p*(p+1))/2+q; } // p<=q
__host__ __device__ constexpr int SIDX(int a,int b){ return (a<=b)?TRI(a,b):TRI(b,a); }
__host__ __device__ constexpr int LTRI(int i,int j){ return i*(i+1)/2+j; }       // j<=i

template<int CTRL>
__device__ __forceinline__ float dpp_add(float v){
  int s = __builtin_amdgcn_mov_dpp(__float_as_int(v), CTRL, 0xF, 0xF, true);
  return v + __int_as_float(s);
}
// 16-lane group sum (DPP row = 16 lanes)
__device__ __forceinline__ float gsum16(float v){
  v = dpp_add<0xB1>(v);    // quad xor1
  v = dpp_add<0x4E>(v);    // quad xor2
  v = dpp_add<0x141>(v);   // row_half_mirror
  v = dpp_add<0x140>(v);   // row_mirror
  return v;
}

__global__ __launch_bounds__(256,2) void pace_fused(const float* __restrict__ y,
                                                    const float* __restrict__ w,
                                                    const float* __restrict__ mk,
                                                    float* __restrict__ out){
  __shared__ __attribute__((aligned(16))) float sc[3600];     // coef rows [n][36]
  __shared__ float sm[SM_SIZE];
  __shared__ __attribute__((aligned(16))) float arena[AR_SIZE];
  const int tid  = threadIdx.x;
  const int lane = tid & 63;
  const int sub  = tid & 15;
  const int item = tid >> 4;                 // 0..15
  const int gb   = blockIdx.x*16 + item;
  const float* yb = y + gb*300;

  // ================= Phase P: per-block precompute (identical across blocks) =================
  {
    float* s_mb = arena;          // 3000: mk staged, then bar_b in place
    float* s_w  = arena+3000;
    float* s_sw = arena+3104;
    float* s_bw = arena+3208;
    float* s_C  = arena+3240;
    float* s_Hi = arena+3340;
    float* s_G  = arena+3440;
    float* s_T  = arena+3540;
    float* s_gv = arena+3640;
    float* s_Ht = arena+3656;
    float* s_z  = arena+3672;

    for (int i=tid;i<3000;i+=256) s_mb[i]=mk[i];
    for (int i=tid;i<100;i+=256){ float x=w[i]; s_w[i]=x; s_sw[i]=sqrtf(x); }
    __syncthreads();

    // wsum: per-wave butterfly (identical in all waves)
    float av = s_w[lane] + ((lane<36)? s_w[lane+64] : 0.f);
    #pragma unroll
    for (int m=32;m;m>>=1) av += __shfl_xor(av,m);
    const float wsum = av;
    const float rws  = 1.0f/av;

    if (tid<30){      // b_w rows
      const float4* p=(const float4*)&s_mb[tid*100];
      const float4* q=(const float4*)&s_w[0];
      float acc=0;
      #pragma unroll 5
      for (int j=0;j<25;j++){ float4 x=p[j], yv=q[j];
        acc=fmaf(x.x,yv.x,acc); acc=fmaf(x.y,yv.y,acc);
        acc=fmaf(x.z,yv.z,acc); acc=fmaf(x.w,yv.w,acc); }
      s_bw[tid]=acc*rws;
    }
    __syncthreads();
    for (int i=tid;i<3000;i+=256){ int r=i/100, n=i-r*100; s_mb[i]=s_sw[n]*(s_mb[i]-s_bw[r]); }
    __syncthreads();
    // C = bar_B^T bar_B from LDS (one element per thread, tid<100)
    if (tid<100){
      int k=tid/10, k2=tid-10*(tid/10);
      const float4* p1=(const float4*)&s_mb[k*300];
      const float4* p2=(const float4*)&s_mb[k2*300];
      float acc=0;
      #pragma unroll 5
      for (int j=0;j<75;j++){ float4 x=p1[j], yv=p2[j];
        acc=fmaf(x.x,yv.x,acc); acc=fmaf(x.y,yv.y,acc);
        acc=fmaf(x.z,yv.z,acc); acc=fmaf(x.w,yv.w,acc); }
      s_C[tid]=acc;
    }
    __syncthreads();
    // Gauss-Jordan inversion of 2(C+I): wave0 lanes 0..9 own rows
    if (tid<64){
      float R[20];
      {
        int row=(tid<10)? tid : 0;
        #pragma unroll
        for (int c=0;c<10;c++) R[c]=2.0f*(s_C[row*10+c]+(c==row?1.0f:0.0f));
        #pragma unroll
        for (int c=0;c<10;c++) R[10+c]=(c==row)?1.0f:0.0f;
      }
      #pragma unroll
      for (int p=0;p<10;p++){
        float appv=__shfl(R[p],p);
        float ra=1.0f/appv;
        float fr=R[p];
        #pragma unroll
        for (int c=0;c<20;c++){
          float pc=__shfl(R[c],p)*ra;
          R[c]=(tid==p)? pc : fmaf(-fr,pc,R[c]);
        }
      }
      if (tid<10){
        float ht=0.f;
        #pragma unroll
        for (int c=0;c<10;c++){ s_Hi[tid*10+c]=R[10+c]; ht+=R[10+c]; }
        s_Ht[tid]=ht;
      }
    }
    __syncthreads();
    // denom from LDS (uniform across all threads)
    float dsum=0.f;
    #pragma unroll
    for (int k=0;k<10;k++) dsum+=s_Ht[k];
    const float rden=1.0f/dsum;
    if (tid<10) s_gv[tid]=s_Ht[tid]*rden;
    __syncthreads();
    if (tid<100){ int r=tid/10,c=tid-10*(tid/10); s_G[tid]=s_Hi[tid]-s_Ht[r]*s_Ht[c]*rden; }
    __syncthreads();
    if (tid<100){         // T = (C+I)G
      int r=tid/10,c=tid-10*(tid/10); float acc=0;
      #pragma unroll
      for (int j=0;j<10;j++) acc+=(s_C[r*10+j]+(r==j?1.0f:0.0f))*s_G[j*10+c];
      s_T[tid]=acc;
    }
    __syncthreads();
    if (tid<100){         // W = 4G(C+I)G - 4G ; emit G
      int r=tid/10,c=tid-10*(tid/10); float acc=0;
      #pragma unroll
      for (int j=0;j<10;j++) acc+=s_G[r*10+j]*s_T[j*10+c];
      sm[SM_W+tid]=4.0f*acc-4.0f*s_G[tid];
      sm[SM_G+tid]=s_G[tid];
    }
    if (tid<10){          // z = (C+I)g
      float acc=0;
      #pragma unroll
      for (int j=0;j<10;j++) acc+=(s_C[tid*10+j]+(tid==j?1.0f:0.0f))*s_gv[j];
      s_z[tid]=acc;
    }
    __syncthreads();
    if (tid<10){          // z2 = 2Gz - g
      float acc=0;
      #pragma unroll
      for (int j=0;j<10;j++) acc+=s_G[tid*10+j]*s_z[j];
      sm[SM_Z2+tid]=2.0f*acc-s_gv[tid];
    }
    if (tid==0){          // q00 = g^T C g + g.g (serial, tiny)
      float acc=0;
      #pragma unroll
      for (int r=0;r<10;r++){
        float rr=0;
        #pragma unroll
        for (int c=0;c<10;c++) rr+=s_C[r*10+c]*s_gv[c];
        acc+=s_gv[r]*rr+s_gv[r]*s_gv[r];
      }
      sm[SM_WSUM]=wsum; sm[SM_RWS]=rws; sm[SM_Q00]=acc; sm[3]=0.f;
    }
    // coef rows [n][36]: {w, coef0..29, pad5}; coef = sw*barb = w*(b-bw)
    for (int i=tid;i<3600;i+=256){
      int n=i/36, e=i-36*n; float v;
      if (e==0) v=s_w[n];
      else if (e>=31) v=0.f;
      else v=s_mb[(e-1)*100+n]*s_sw[n];
      sc[i]=v;
    }
    if (tid<30){          // bs[k,j] = sum_n barb*sw
      const float4* p=(const float4*)&s_mb[tid*100];
      const float4* q=(const float4*)&s_sw[0];
      float acc=0;
      #pragma unroll 5
      for (int j=0;j<25;j++){ float4 x=p[j], yv=q[j];
        acc=fmaf(x.x,yv.x,acc); acc=fmaf(x.y,yv.y,acc);
        acc=fmaf(x.z,yv.z,acc); acc=fmaf(x.w,yv.w,acc); }
      sm[SM_BS+tid]=acc;
    }
    if (tid<10) sm[SM_GV+tid]=s_gv[tid];
    if (tid<30) sm[SM_BW+tid]=s_bw[tid];
    __syncthreads();   // Phase P done; arena reusable
  }

  // ================= Phase A: 16 lanes per item =================
  float* sF  = arena;          // [16][90]
  float* sQl = arena+1440;     // [16][57]  (stride 57: conflict-free lane reads)
  float* sG3 = arena+2352;     // [16][9]
  float* sYW = arena+2496;     // [16][4]

  {
    float F0[90];
    #pragma unroll
    for (int i=0;i<90;i++) F0[i]=0.f;
    float swy0=0,swy1=0,swy2=0,s00=0,s01=0,s02=0,s11=0,s12=0,s22=0;

    auto point=[&](int n){
      float y0=yb[n], y1=yb[100+n], y2=yb[200+n];
      float c[32];
      const float4* cp=(const float4*)&sc[n*36];
      #pragma unroll
      for (int r=0;r<8;r++) ((float4*)c)[r]=cp[r];
      float wn=c[0];
      float wy0=wn*y0,wy1=wn*y1,wy2=wn*y2;
      swy0+=wy0;swy1+=wy1;swy2+=wy2;
      s00+=wy0*y0;s01+=wy0*y1;s02+=wy0*y2;s11+=wy1*y1;s12+=wy1*y2;s22+=wy2*y2;
      #pragma unroll
      for (int k=0;k<10;k++){
        #pragma unroll
        for (int j=0;j<3;j++){
          float bcv=c[1+k*3+j];
          F0[k*9+j*3+0]+=bcv*y0;
          F0[k*9+j*3+1]+=bcv*y1;
          F0[k*9+j*3+2]+=bcv*y2;
        }
      }
    };
    #pragma unroll
    for (int m=0;m<6;m++) point(sub+16*m);
    if (sub<4) point(96+sub);

    #pragma unroll
    for (int e=0;e<90;e++) F0[e]=gsum16(F0[e]);
    swy0=gsum16(swy0); swy1=gsum16(swy1); swy2=gsum16(swy2);
    s00=gsum16(s00); s01=gsum16(s01); s02=gsum16(s02);
    s11=gsum16(s11); s12=gsum16(s12); s22=gsum16(s22);

    const float wsum=sm[SM_WSUM], rws=sm[SM_RWS];
    const float yw0=swy0*rws, yw1=swy1*rws, yw2=swy2*rws;
    #pragma unroll
    for (int k=0;k<10;k++){
      float bs0=sm[SM_BS+k*3+0],bs1=sm[SM_BS+k*3+1],bs2=sm[SM_BS+k*3+2];
      F0[k*9+0]-=yw0*bs0; F0[k*9+1]-=yw1*bs0; F0[k*9+2]-=yw2*bs0;
      F0[k*9+3]-=yw0*bs1; F0[k*9+4]-=yw1*bs1; F0[k*9+5]-=yw2*bs1;
      F0[k*9+6]-=yw0*bs2; F0[k*9+7]-=yw1*bs2; F0[k*9+8]-=yw2*bs2;
    }
    // store F with STATIC indices only (lane-varying index into F0 => scratch demotion, R7 bug)
    if (sub==0){
      #pragma unroll
      for (int e=0;e<90;e++) sF[item*90+e]=F0[e];
      sG3[item*9+0]=s00-wsum*yw0*yw0;
      sG3[item*9+4]=s11-wsum*yw1*yw1;
      sG3[item*9+8]=s22-wsum*yw2*yw2;
      float g01=s01-wsum*yw0*yw1, g02=s02-wsum*yw0*yw2, g12=s12-wsum*yw1*yw2;
      sG3[item*9+1]=g01; sG3[item*9+3]=g01;
      sG3[item*9+2]=g02; sG3[item*9+6]=g02;
      sG3[item*9+5]=g12; sG3[item*9+7]=g12;
      sYW[item*4+0]=yw0; sYW[item*4+1]=yw1; sYW[item*4+2]=yw2;
    }
  }
  __syncthreads();

  // ---- Q assembly: 144 column tasks (item,mp) + 16 q00 writes ----
  if (tid<144){
    int it2=tid/9, mp=tid-9*(tid/9);
    float fcol[10], t2[10];
    #pragma unroll
    for (int k=0;k<10;k++) fcol[k]=sF[it2*90+k*9+mp];
    #pragma unroll
    for (int k=0;k<10;k++){
      float acc=0;
      #pragma unroll
      for (int k2=0;k2<10;k2++) acc+=sm[SM_W+k*10+k2]*fcol[k2];
      t2[k]=acc;
    }
    float he=0;
    #pragma unroll
    for (int k=0;k<10;k++) he+=sm[SM_Z2+k]*fcol[k];
    sQl[it2*57 + 1+mp]=he;
    #pragma unroll 1
    for (int m=0;m<=mp;m++){
      float gd=sG3[it2*9+(m%3)*3+(mp%3)];
      float acc=((m/3)==(mp/3))? gd : 0.f;
      #pragma unroll
      for (int k=0;k<10;k++) acc+=sF[it2*90+k*9+m]*t2[k];
      int p=1+m, q=1+mp;
      sQl[it2*57 + p*10-((p*(p+1))>>1)+q]=acc;
    }
  }
  if (tid>=144 && tid<160) sQl[(tid-144)*57]=sm[SM_Q00];
  __syncthreads();

  // ================= Eigen + epilogue: one item per thread (tid<16) =================
  if (tid<16){
    const int it2=tid;
    const int gb2=blockIdx.x*16+it2;
    float A[55];
    #pragma unroll
    for (int e=0;e<55;e++) A[e]=sQl[it2*57+e];
    float dd[10], ee[9];
    #pragma unroll
    for (int k=0;k<8;k++){
      float nrm2=0.f;
      #pragma unroll
      for (int i=1;i<10;i++){ if (i<k+1) continue; float xi=A[SIDX(i,k)]; nrm2=fmaf(xi,xi,nrm2); }
      float x0=A[SIDX(k+1,k)];
      float nr=sqrtf(nrm2);
      float alpha=-copysignf(nr,x0);
      bool ok=nrm2>1e-30f;
      float v1=x0-alpha;
      float vtv=-2.0f*alpha*v1;
      float bh=ok?2.0f*__builtin_amdgcn_rcpf(vtv):0.f;
      ee[k]=ok?alpha:x0;
      float vv[10];
      #pragma unroll
      for (int i=0;i<10;i++) vv[i]=(i<k+1)?0.f:((i==k+1)?v1:A[SIDX(i,k)]);
      float p[10];
      #pragma unroll
      for (int i=0;i<10;i++){
        if (i<k+1){ p[i]=0.f; continue; }
        float acc=0;
        #pragma unroll
        for (int j=1;j<10;j++){ if (j<k+1) continue; acc+=A[SIDX(i,j)]*vv[j]; }
        p[i]=bh*acc;
      }
      float Kc=0.f;
      #pragma unroll
      for (int i=1;i<10;i++){ if (i<k+1) continue; Kc=fmaf(vv[i],p[i],Kc); }
      Kc*=0.5f*bh;
      float wv[10];
      #pragma unroll
      for (int i=0;i<10;i++) wv[i]=p[i]-Kc*vv[i];
      #pragma unroll
      for (int i=1;i<10;i++){
        if (i<k+1) continue;
        #pragma unroll
        for (int j=1;j<10;j++){
          if (j<i) continue;
          A[TRI(i,j)]-=vv[i]*wv[j]+wv[i]*vv[j];
        }
      }
    }
    ee[8]=A[TRI(8,9)];
    #pragma unroll
    for (int i=0;i<10;i++) dd[i]=A[TRI(i,i)];
    float esq[9];
    #pragma unroll
    for (int i=0;i<9;i++) esq[i]=ee[i]*ee[i];

    // Gershgorin bracket + serial bisection (16 iters, branch-free updates)
    float scaleT=0.f, lo=1e30f, hi=1e30f;
    #pragma unroll
    for (int i=0;i<10;i++){
      float r=((i>0)?fabsf(ee[i-1]):0.f)+((i<9)?fabsf(ee[i]):0.f);
      scaleT=fmaxf(scaleT,fabsf(dd[i])+r);
      lo=fminf(lo,dd[i]-r);
      hi=fminf(hi,dd[i]);
    }
    hi+=1e-6f*scaleT+1e-30f;
    const float pm=1e-12f*scaleT+1e-37f;
    #pragma unroll 1
    for (int it=0;it<16;++it){
      float mid=0.5f*(lo+hi);
      float q=dd[0]-mid;
      q=(fabsf(q)<pm)?((q<0.f)?-pm:pm):q;
      int cnt=(q<0.f);
      #pragma unroll
      for (int i=1;i<10;i++){
        q=dd[i]-mid-esq[i-1]*__builtin_amdgcn_rcpf(q);
        q=(fabsf(q)<pm)?((q<0.f)?-pm:pm):q;
        cnt+=(q<0.f);
      }
      bool any=cnt>0;
      hi=any?mid:hi;
      lo=any?lo:mid;
    }
    const float sigma=lo-1e-5f*scaleT-1e-30f;   // cnt(sigma)==0; margin caps amplification
    const float pmL=1e-8f*scaleT+1e-37f;

    // dense Cholesky of (Q - sigma I) from LDS; overflow rails
    float Lc[55], rd[10];
    #pragma unroll
    for (int i=0;i<10;i++){
      #pragma unroll
      for (int j=0;j<10;j++){
        if (j>i) continue;
        float a=sQl[it2*57+SIDX(j,i)]-((i==j)?sigma:0.f);
        #pragma unroll
        for (int t2=0;t2<9;t2++){
          if (t2>=j) continue;
          a-=Lc[LTRI(i,t2)]*Lc[LTRI(j,t2)];
        }
        if (j<i) Lc[LTRI(i,j)]=a*rd[j];
        else { a=fmaxf(a,pmL); rd[i]=rsqrtf(a); Lc[LTRI(i,i)]=a*rd[i]; }
      }
    }
    float xv[10];
    #pragma unroll
    for (int i=0;i<10;i++) xv[i]=1.f;
    #pragma unroll 1
    for (int itr=0;itr<3;++itr){
      #pragma unroll
      for (int i=0;i<10;i++){
        float acc=xv[i];
        #pragma unroll
        for (int j=0;j<9;j++){ if (j>=i) continue; acc-=Lc[LTRI(i,j)]*xv[j]; }
        acc*=rd[i];
        xv[i]=fminf(fmaxf(acc,-1e15f),1e15f);
      }
      #pragma unroll
      for (int i=9;i>=0;i--){
        float acc=xv[i];
        #pragma unroll
        for (int j=9;j>0;j--){ if (j<=i) continue; acc-=Lc[LTRI(j,i)]*xv[j]; }
        acc*=rd[i];
        xv[i]=fminf(fmaxf(acc,-1e15f),1e15f);
      }
      float nn=0.f;
      #pragma unroll
      for (int i=0;i<10;i++) nn=fmaf(xv[i],xv[i],nn);
      nn=fmaxf(nn,1e-30f);
      float sc2=rsqrtf(nn);
      #pragma unroll
      for (int i=0;i<10;i++) xv[i]*=sc2;
    }
    float r0=1.0f/xv[0];
    float vn[10];
    vn[0]=1.f;
    #pragma unroll
    for (int m=1;m<10;m++) vn[m]=xv[m]*r0;

    // epilogue
    float dv[10];
    #pragma unroll
    for (int k=0;k<10;k++){
      float acc=0;
      #pragma unroll
      for (int m=0;m<9;m++) acc+=vn[1+m]*sF[it2*90+k*9+m];
      dv[k]=acc;
    }
    float cv[10];
    #pragma unroll
    for (int k=0;k<10;k++){
      float acc=0;
      #pragma unroll
      for (int k2=0;k2<10;k2++) acc+=sm[SM_G+k*10+k2]*dv[k2];
      cv[k]=2.0f*acc+sm[SM_GV+k];
    }
    float e0=0,e1=0,e2=0;
    #pragma unroll
    for (int k=0;k<10;k++){
      e0+=sm[SM_BW+k*3+0]*cv[k];
      e1+=sm[SM_BW+k*3+1]*cv[k];
      e2+=sm[SM_BW+k*3+2]*cv[k];
    }
    float yw0=sYW[it2*4+0], yw1=sYW[it2*4+1], yw2=sYW[it2*4+2];
    #pragma unroll
    for (int i=0;i<3;i++)
      #pragma unroll
      for (int j=0;j<3;j++)
        out[gb2*9+i*3+j]=vn[1+3*j+i];
    out[73728+gb2*3+0]=yw0-(vn[1]*e0+vn[4]*e1+vn[7]*e2);
    out[73728+gb2*3+1]=yw1-(vn[2]*e0+vn[5]*e1+vn[8]*e2);
    out[73728+gb2*3+2]=yw2-(vn[3]*e0+vn[6]*e1+vn[9]*e2);
    #pragma unroll
    for (int k=0;k<10;k++)
      out[98304+gb2*10+k]=cv[k];
  }
}

extern "C" void kernel_launch(void* const* d_in, const int* in_sizes, int n_in,
                              void* d_out, int out_size, void* d_ws, size_t ws_size,
                              hipStream_t stream) {
  const float* y  = (const float*)d_in[0];   // (8192,3,100)
  const float* w  = (const float*)d_in[1];   // (100,1)
  const float* mk = (const float*)d_in[2];   // (10,3,100)
  float* out = (float*)d_out;                // R(8192*9) | t(8192*3) | c(8192*10)
  pace_fused<<<512, 256, 0, stream>>>(y, w, mk, out);
}